// Round 11
// baseline (1885.951 us; speedup 1.0000x reference)
//
#include <hip/hip_runtime.h>
#include <stdint.h>

#define B_ 16384
#define S_ 336
#define T_ 48
#define IN_ 5
#define H_ 64

#define ROWS 64              // batch rows per block (one 32-row tile per rt)

typedef _Float16 f16;
typedef _Float16 f16x8 __attribute__((ext_vector_type(8)));
typedef float f32x16 __attribute__((ext_vector_type(16)));

#define LOG2E 1.44269504088896340736f

// ---- ws layout (f32 words) ----
// 32x32x16 A-fragments: [gt8][kc][lane64][w4] u32 words, f16 single plane.
// Weights & biases PRE-SCALED: gate rows i,f,o by -log2e, gate g by +2*log2e.
// L0 chunk0: x at k0..4, bias at k5. L1 chunk8: bias at k0 (B-side one-hot).
#define NKC0 5
#define NKC1 9
#define OFF_E0 0                         // 8*5*256 = 10240
#define OFF_E1 10240                     // 8*9*256 = 18432
#define OFF_D0 28672
#define OFF_D1 38912                     // ends 57344
#define OFF_FCW 57344
#define OFF_FCB 57408
#define WS_TOT  57409

__device__ __forceinline__ float sig2(float g) {     // sigmoid(z), g = -log2e*z
    return __builtin_amdgcn_rcpf(1.0f + __builtin_amdgcn_exp2f(g));
}
__device__ __forceinline__ float tanh2(float g) {    // tanh(z), g = 2*log2e*z
    return 1.0f - 2.0f * __builtin_amdgcn_rcpf(1.0f + __builtin_amdgcn_exp2f(g));
}
__device__ __forceinline__ float tanhc(float c) {    // tanh(c), raw c
    return 1.0f - 2.0f * __builtin_amdgcn_rcpf(1.0f + __builtin_amdgcn_exp2f(c * (2.0f * LOG2E)));
}

// ---------------- prep: pack weights into 32x32x16 A-fragment layout ----
// A elem (gt,kc,lane,w,hf): gate row gr = lane&31 (= q*4+type, q=unit-in-tile),
// j = type*64 + gt*8 + q; k_local = (lane>>5)*8 + w*2 + hf.
__global__ void prep_kernel(
    const float* __restrict__ eWih0, const float* __restrict__ eWhh0,
    const float* __restrict__ ebih0, const float* __restrict__ ebhh0,
    const float* __restrict__ eWih1, const float* __restrict__ eWhh1,
    const float* __restrict__ ebih1, const float* __restrict__ ebhh1,
    const float* __restrict__ dWih0, const float* __restrict__ dWhh0,
    const float* __restrict__ dbih0, const float* __restrict__ dbhh0,
    const float* __restrict__ dWih1, const float* __restrict__ dWhh1,
    const float* __restrict__ dbih1, const float* __restrict__ dbhh1,
    const float* __restrict__ fcW,  const float* __restrict__ fcb,
    float* __restrict__ ws)
{
    int idx = blockIdx.x * blockDim.x + threadIdx.x;
    if (idx >= WS_TOT) return;
    float outv;
    if (idx < OFF_FCW) {
        int off, nkc, which;
        if (idx < OFF_E1)      { off = OFF_E0; nkc = NKC0; which = 0; }
        else if (idx < OFF_D0) { off = OFF_E1; nkc = NKC1; which = 1; }
        else if (idx < OFF_D1) { off = OFF_D0; nkc = NKC0; which = 2; }
        else                   { off = OFF_D1; nkc = NKC1; which = 3; }
        int rel = idx - off;
        int w = rel & 3, lane = (rel >> 2) & 63;
        int rest = rel >> 8;
        int kc = rest % nkc, gt = rest / nkc;
        int gr = lane & 31;
        int q = gr >> 2, type = gr & 3;
        int j = type * 64 + gt * 8 + q;
        float sc = (type == 2) ? (2.0f * LOG2E) : (-LOG2E);
        union { f16 h2[2]; float f; } u_;
        #pragma unroll
        for (int hf = 0; hf < 2; ++hf) {
            int kl = (lane >> 5) * 8 + w * 2 + hf;
            float v = 0.0f;
            if (which == 0) {            // enc L0
                if (kc == 0) {
                    if (kl < IN_)      v = eWih0[j * IN_ + kl];
                    else if (kl == 5)  v = ebih0[j] + ebhh0[j];
                } else                   v = eWhh0[j * 64 + (kc - 1) * 16 + kl];
            } else if (which == 1) {     // enc L1
                if (kc < 4)            v = eWih1[j * 64 + kc * 16 + kl];
                else if (kc < 8)       v = eWhh1[j * 64 + (kc - 4) * 16 + kl];
                else if (kl == 0)      v = ebih1[j] + ebhh1[j];   // bias chunk
            } else if (which == 2) {     // dec L0
                if (kc == 0) {
                    if (kl == 0)       v = dWih0[j];
                    else if (kl == 5)  v = dbih0[j] + dbhh0[j];
                } else                   v = dWhh0[j * 64 + (kc - 1) * 16 + kl];
            } else {                     // dec L1
                if (kc < 4)            v = dWih1[j * 64 + kc * 16 + kl];
                else if (kc < 8)       v = dWhh1[j * 64 + (kc - 4) * 16 + kl];
                else if (kl == 0)      v = dbih1[j] + dbhh1[j];
            }
            u_.h2[hf] = (f16)(v * sc);
        }
        outv = u_.f;
    } else if (idx < OFF_FCB) {
        outv = fcW[idx - OFF_FCW];
    } else {
        outv = fcb[0];
    }
    ws[idx] = outv;
}

// LDS layouts (f16 element index). B-frag read: lane l -> hf = l>>5,
// col/row = rt*32 + (l&31); k = kc*16 + hf*8 + j.
__device__ __forceinline__ int xbi(int b, int pl, int hf, int row) {
    return ((((b * 2 + pl) * 2 + hf) * 64) + row) * 8;
}
__device__ __forceinline__ int hbi(int b, int pl, int kc, int hf, int row) {
    return (((((b * 2 + pl) * 4 + kc) * 2 + hf) * 64) + row) * 8;
}
#define XTOT  (2*2*2*64*8)     // 4096 f16 = 8 KB
#define HTOT  (2*2*4*2*64*8)   // 16384 f16 = 32 KB
#define HHALF (2*4*2*64*8)     // one buf = 8192 f16
#define PLSTR (4*2*64*8)       // pl stride within buf = 4096 f16

#define MFMA32(a,b,c) __builtin_amdgcn_mfma_f32_32x32x16_f16(a, b, c, 0, 0, 0)

__device__ __forceinline__ void stage_x5(f16* __restrict__ XB, int b, int r, const float* xv) {
    f16x8 ph = {}, pl_ = {}, zz = {};
    #pragma unroll
    for (int i = 0; i < IN_; ++i) {
        f16 hh = (f16)xv[i]; ph[i] = hh; pl_[i] = (f16)(xv[i] - (float)hh);
    }
    ph[5] = (f16)1.0f;          // bias slot (k=5)
    *(f16x8*)&XB[xbi(b,0,0,r)] = ph;
    *(f16x8*)&XB[xbi(b,0,1,r)] = zz;
    *(f16x8*)&XB[xbi(b,1,0,r)] = pl_;
    *(f16x8*)&XB[xbi(b,1,1,r)] = zz;
}
__device__ __forceinline__ void stage_x1(f16* __restrict__ XB, int b, int r, float v) {
    f16x8 ph = {}, pl_ = {}, zz = {};
    f16 hh = (f16)v; ph[0] = hh; pl_[0] = (f16)(v - (float)hh);
    ph[5] = (f16)1.0f;
    *(f16x8*)&XB[xbi(b,0,0,r)] = ph;
    *(f16x8*)&XB[xbi(b,0,1,r)] = zz;
    *(f16x8*)&XB[xbi(b,1,0,r)] = pl_;
    *(f16x8*)&XB[xbi(b,1,1,r)] = zz;
}

// activation+store for one bundle (unit qi of this wave's tile).
// acc regs 4qi..4qi+3 = gates i,f,g,o of unit u = gt*8 + 2*qi + hf, col = row.
__device__ __forceinline__ void act_store(
    float gi, float gf, float gg_, float go, float& c, int qi,
    int gt, int hf, int row, int b, f16* __restrict__ H, float* __restrict__ H1F)
{
    float ig = sig2(gi), fg = sig2(gf);
    float gg = tanh2(gg_), og = sig2(go);
    float cc = fmaf(fg, c, ig * gg);
    c = cc;
    float h = og * tanhc(cc);
    f16 hh = (f16)h, hl = (f16)(h - (float)hh);
    int u = gt * 8 + 2 * qi + hf;
    int base = hbi(b, 0, u >> 4, (u >> 3) & 1, row) + (u & 7);
    H[base] = hh;
    H[base + PLSTR] = hl;
    if (H1F) H1F[u * 65 + row] = h;
}

// ---- standalone layer 0 (prologue + decoder): z = W0 @ [x|h0_prev], bias in x k5
__device__ __forceinline__ void layer0_only(
    int pX, int pH0r, int pH0w, int gt, int hf, int row,
    const f16x8 (&wa0)[NKC0], float (&c0)[4],
    const f16* __restrict__ XB, f16* __restrict__ H0B)
{
    f32x16 z = {};
    #pragma unroll
    for (int kc = 0; kc < 4; ++kc) {
        f16x8 hh = *(const f16x8*)&H0B[hbi(pH0r,0,kc,hf,row)];
        f16x8 hl = *(const f16x8*)&H0B[hbi(pH0r,1,kc,hf,row)];
        z = MFMA32(wa0[1+kc], hh, z);
        z = MFMA32(wa0[1+kc], hl, z);
    }
    {
        f16x8 xh = *(const f16x8*)&XB[xbi(pX,0,hf,row)];
        f16x8 xl = *(const f16x8*)&XB[xbi(pX,1,hf,row)];
        z = MFMA32(wa0[0], xh, z);
        z = MFMA32(wa0[0], xl, z);
    }
    #pragma unroll
    for (int qi = 0; qi < 4; ++qi)
        act_store(z[4*qi], z[4*qi+1], z[4*qi+2], z[4*qi+3], c0[qi], qi,
                  gt, hf, row, pH0w, H0B, nullptr);
}

// ---- standalone layer 1 (epilogue + decoder): a = W1 @ [h0|h1_prev] + bias chunk
template<bool DEC>
__device__ __forceinline__ void layer1_only(
    int pH0, int pH1r, int pH1w, int gt, int hf, int row,
    const f16x8 (&wa1)[NKC1], f16x8 bvec, float (&c1)[4],
    const f16* __restrict__ H0B, f16* __restrict__ H1B, float* __restrict__ H1F)
{
    f32x16 a = {};
    a = MFMA32(wa1[8], bvec, a);            // bias (B one-hot at k0)
    #pragma unroll
    for (int kc = 0; kc < 4; ++kc) {
        f16x8 hh = *(const f16x8*)&H0B[hbi(pH0,0,kc,hf,row)];
        f16x8 hl = *(const f16x8*)&H0B[hbi(pH0,1,kc,hf,row)];
        a = MFMA32(wa1[kc], hh, a);
        a = MFMA32(wa1[kc], hl, a);
    }
    #pragma unroll
    for (int kc = 0; kc < 4; ++kc) {
        f16x8 gh = *(const f16x8*)&H1B[hbi(pH1r,0,kc,hf,row)];
        f16x8 gl = *(const f16x8*)&H1B[hbi(pH1r,1,kc,hf,row)];
        a = MFMA32(wa1[4+kc], gh, a);
        a = MFMA32(wa1[4+kc], gl, a);
    }
    #pragma unroll
    for (int qi = 0; qi < 4; ++qi)
        act_store(a[4*qi], a[4*qi+1], a[4*qi+2], a[4*qi+3], c1[qi], qi,
                  gt, hf, row, pH1w, H1B, DEC ? H1F : nullptr);
}

// ---- fused encoder phase t: {L1_t ; L0_{t+1}} — ONE barrier per timestep.
// SINGLE-ACCUMULATOR version (R10): finish the L1_t chain (MFMA -> act ->
// store), then REUSE the same f32x16 for L0_{t+1} (re-reading h0 frags from
// LDS: +8 ds_read_b128, trivial). R8/R9 kept both 16-reg accs live across
// the phase -> ~130-reg live set > the hard 128 unified budget at 4 waves/EU
// -> 43 MB scratch spill. L1's act VALU overlaps the following independent
// L0 MFMA chain in issue order; 4 waves/SIMD give cross-wave overlap.
__device__ __forceinline__ void enc_phase(
    int p, int gt, int hf, int row,
    const f16x8 (&wa0)[NKC0], const f16x8 (&wa1)[NKC1], f16x8 bvec,
    float (&c0)[4], float (&c1)[4],
    const f16* __restrict__ XB, f16* __restrict__ H0B, f16* __restrict__ H1B)
{
    const int q = p ^ 1;
    f32x16 acc;
    // ---- chain 1: L1_t = W1 @ [h0_t | h1_{t-1}] + bias ----
    acc = (f32x16){};
    acc = MFMA32(wa1[8], bvec, acc);
    #pragma unroll
    for (int kc = 0; kc < 4; ++kc) {
        f16x8 hh = *(const f16x8*)&H0B[hbi(p,0,kc,hf,row)];
        f16x8 hl = *(const f16x8*)&H0B[hbi(p,1,kc,hf,row)];
        acc = MFMA32(wa1[kc], hh, acc);
        acc = MFMA32(wa1[kc], hl, acc);
    }
    #pragma unroll
    for (int kc = 0; kc < 4; ++kc) {
        f16x8 gh = *(const f16x8*)&H1B[hbi(q,0,kc,hf,row)];
        f16x8 gl = *(const f16x8*)&H1B[hbi(q,1,kc,hf,row)];
        acc = MFMA32(wa1[4+kc], gh, acc);
        acc = MFMA32(wa1[4+kc], gl, acc);
    }
    #pragma unroll
    for (int qi = 0; qi < 4; ++qi)
        act_store(acc[4*qi], acc[4*qi+1], acc[4*qi+2], acc[4*qi+3], c1[qi], qi,
                  gt, hf, row, p, H1B, nullptr);

    // ---- chain 2: L0_{t+1} = W0 @ [x_{t+1} | h0_t]  (same acc regs) ----
    acc = (f32x16){};
    #pragma unroll
    for (int kc = 0; kc < 4; ++kc) {
        f16x8 hh = *(const f16x8*)&H0B[hbi(p,0,kc,hf,row)];
        f16x8 hl = *(const f16x8*)&H0B[hbi(p,1,kc,hf,row)];
        acc = MFMA32(wa0[1+kc], hh, acc);
        acc = MFMA32(wa0[1+kc], hl, acc);
    }
    {
        f16x8 xh = *(const f16x8*)&XB[xbi(q,0,hf,row)];
        f16x8 xl = *(const f16x8*)&XB[xbi(q,1,hf,row)];
        acc = MFMA32(wa0[0], xh, acc);
        acc = MFMA32(wa0[0], xl, acc);
    }
    #pragma unroll
    for (int qi = 0; qi < 4; ++qi)
        act_store(acc[4*qi], acc[4*qi+1], acc[4*qi+2], acc[4*qi+3], c0[qi], qi,
                  gt, hf, row, q, H0B, nullptr);
}

// 1024 threads = 16 waves; wave = gt*2 + rt owns one 32-gate x 32-row tile of
// BOTH L1_t and L0_{t+1}. ROWS=64/block, grid=256 (1/CU). Single f32x16 acc
// (R10) keeps the live set ~110 < 128 unified budget at the LDS-forced
// 4 waves/EU. waves_per_eu(4,4) documents the operating point (caps at 128).
__global__ __launch_bounds__(1024)
__attribute__((amdgpu_waves_per_eu(4, 4)))
void lstm_kernel(
    const float* __restrict__ src, const float* __restrict__ ws,
    float* __restrict__ out)
{
    __shared__ __align__(16) f16 XB [XTOT];   // 8 KB
    __shared__ __align__(16) f16 H0B[HTOT];   // 32 KB
    __shared__ __align__(16) f16 H1B[HTOT];   // 32 KB
    __shared__ float H1F[64 * 65];            // 16.25 KB (decoder fc)
    __shared__ float FCW[64];

    const int tid  = threadIdx.x;
    const int lane = tid & 63;
    const int wave = __builtin_amdgcn_readfirstlane(tid >> 6);
    const int gt   = wave >> 1;
    const int rt   = wave & 1;
    const int hf   = lane >> 5;
    const int row  = rt * 32 + (lane & 31);
    const int rowBase = blockIdx.x * ROWS;

    float c0[4], c1[4];
    #pragma unroll
    for (int i = 0; i < 4; ++i) { c0[i] = 0.0f; c1[i] = 0.0f; }

    f16x8 wa0[NKC0], wa1[NKC1];
    f16x8 bvec = {};
    if (hf == 0) bvec[0] = (f16)1.0f;   // one-hot B for the bias chunk (k=0)

    auto ldw = [&](int off0, int off1) {
        #pragma unroll
        for (int kc = 0; kc < NKC0; ++kc)
            wa0[kc] = *(const f16x8*)(ws + off0 + ((gt * NKC0 + kc) * 64 + lane) * 4);
        #pragma unroll
        for (int kc = 0; kc < NKC1; ++kc)
            wa1[kc] = *(const f16x8*)(ws + off1 + ((gt * NKC1 + kc) * 64 + lane) * 4);
    };
    ldw(OFF_E0, OFF_E1);

    // zero parity-1 halves of H0B/H1B (h0_{-1} = h1_{-1} = 0)
    for (int i = tid; i < HHALF; i += 1024) { H0B[HHALF + i] = (f16)0; H1B[HHALF + i] = (f16)0; }
    if (tid < 64) FCW[tid] = ws[OFF_FCW + tid];
    const float fcbv = ws[OFF_FCB];

    const float* sp = src + (size_t)(rowBase + lane) * (S_ * IN_);
    __syncthreads();

    // stage x0 -> XB[0], x1 -> XB[1] (wave 15: lane = row, 64 rows)
    if (wave == 15) {
        float xv[IN_];
        #pragma unroll
        for (int i = 0; i < IN_; ++i) xv[i] = sp[i];
        stage_x5(XB, 0, lane, xv);
        #pragma unroll
        for (int i = 0; i < IN_; ++i) xv[i] = sp[IN_ + i];
        stage_x5(XB, 1, lane, xv);
    }
    __syncthreads();

    // prologue: L0_0 (reads XB[0], H0B[1](=0), writes H0B[0])
    layer0_only(0, 1, 0, gt, hf, row, wa0, c0, XB, H0B);
    __syncthreads();

    // ---------------- encoder: fused phases, ONE barrier per timestep ----------
    #pragma unroll 1
    for (int t = 0; t < S_ - 1; ++t) {
        const int p = t & 1;
        float xv[IN_];
        const bool pf = (wave == 15) && (t + 2 < S_);
        if (pf) {
            #pragma unroll
            for (int i = 0; i < IN_; ++i) xv[i] = sp[(t + 2) * IN_ + i];
        }
        enc_phase(p, gt, hf, row, wa0, wa1, bvec, c0, c1, XB, H0B, H1B);
        if (pf) stage_x5(XB, p, lane, xv);   // x_{t+2} -> XB[(t+2)&1] = XB[p]
        __syncthreads();
    }

    // epilogue: L1_{S-1} (reads H0B[1], H1B[0], writes H1B[1])
    layer1_only<false>(1, 0, 1, gt, hf, row, wa1, bvec, c1, H0B, H1B, H1F);
    __syncthreads();

    // ---------------- decoder ----------------
    ldw(OFF_D0, OFF_D1);
    if (wave == 15) stage_x1(XB, 0, lane, sp[(S_ - 1) * IN_ + 3]);   // dec_in0
    __syncthreads();

    #pragma unroll 1
    for (int t = 0; t < T_; ++t) {
        const int q = t & 1;
        layer0_only(q, q ^ 1, q, gt, hf, row, wa0, c0, XB, H0B);
        __syncthreads();
        layer1_only<true>(q, q ^ 1, q, gt, hf, row, wa1, bvec, c1, H0B, H1B, H1F);
        __syncthreads();
        if (wave == 0) {   // fc head: pred = fcW . h1_new + fcb  (lane = row)
            float pv = fcbv;
            #pragma unroll 8
            for (int k = 0; k < 64; ++k) pv = fmaf(FCW[k], H1F[k * 65 + lane], pv);
            out[(size_t)(rowBase + lane) * T_ + t] = pv;
            if (t + 1 < T_) stage_x1(XB, q ^ 1, lane, pv);
        }
        __syncthreads();
    }
}

extern "C" void kernel_launch(void* const* d_in, const int* in_sizes, int n_in,
                              void* d_out, int out_size, void* d_ws, size_t ws_size,
                              hipStream_t stream)
{
    const float* src = (const float*)d_in[0];
    float* ws  = (float*)d_ws;
    float* out = (float*)d_out;

    prep_kernel<<<(WS_TOT + 255) / 256, 256, 0, stream>>>(
        (const float*)d_in[1],  (const float*)d_in[2],
        (const float*)d_in[3],  (const float*)d_in[4],
        (const float*)d_in[5],  (const float*)d_in[6],
        (const float*)d_in[7],  (const float*)d_in[8],
        (const float*)d_in[9],  (const float*)d_in[10],
        (const float*)d_in[11], (const float*)d_in[12],
        (const float*)d_in[13], (const float*)d_in[14],
        (const float*)d_in[15], (const float*)d_in[16],
        (const float*)d_in[17], (const float*)d_in[18],
        ws);

    lstm_kernel<<<B_ / ROWS, 1024, 0, stream>>>(src, ws, out);
}